// Round 11
// baseline (71.823 us; speedup 1.0000x reference)
//
#include <hip/hip_runtime.h>
#include <hip/hip_bf16.h>

// B=2, LQ=LKV=1024, H=8, DQK=DV=64, DQ=DK=DVIN=DOUT=512, SPAN=128, STRIDE=1
#define LQ 1024
#define NH 8
#define DHEAD 64
#define DMODEL 512
#define SPAN 128
#define MROWS 2048   // B*LQ

typedef __attribute__((ext_vector_type(8))) short   bf16x8;
typedef __attribute__((ext_vector_type(4))) float   f32x4;
typedef __attribute__((ext_vector_type(8))) unsigned short us8;

static __device__ __forceinline__ unsigned short f2bf(float f) {
    union { __hip_bfloat16 h; unsigned short u; } cv;
    cv.h = __float2bfloat16(f);
    return cv.u;
}

static __device__ __forceinline__ void gload_lds16(const void* g, void* l) {
    __builtin_amdgcn_global_load_lds((const __attribute__((address_space(1))) void*)g,
                                     (__attribute__((address_space(3))) void*)l, 16, 0, 0);
}

// ---------------------------------------------------------------------------
// Prep: transpose+cast weights: Wt[n][k] = bf16(W[k][n]), 512x512 each
// (unchanged — validated)
// ---------------------------------------------------------------------------
__global__ __launch_bounds__(256) void transposeW(
    const float* __restrict__ W0, const float* __restrict__ W1,
    const float* __restrict__ W2, const float* __restrict__ W3,
    unsigned short* __restrict__ T0, unsigned short* __restrict__ T1,
    unsigned short* __restrict__ T2, unsigned short* __restrict__ T3)
{
    const float* W = blockIdx.z == 0 ? W0 : blockIdx.z == 1 ? W1 : blockIdx.z == 2 ? W2 : W3;
    unsigned short* T = blockIdx.z == 0 ? T0 : blockIdx.z == 1 ? T1 : blockIdx.z == 2 ? T2 : T3;
    __shared__ unsigned short sT[64][72];
    int c = threadIdx.x & 63;
    int r0 = (threadIdx.x >> 6) * 16;
    int n0 = blockIdx.x * 64, k0 = blockIdx.y * 64;
    #pragma unroll
    for (int i = 0; i < 16; ++i) {
        int r = r0 + i;
        sT[c][r] = f2bf(W[(size_t)(k0 + r) * DMODEL + n0 + c]);
    }
    __syncthreads();
    #pragma unroll
    for (int i = 0; i < 16; ++i) {
        int r = r0 + i;
        T[(size_t)(n0 + r) * DMODEL + k0 + c] = sT[r][c];
    }
}

// ---------------------------------------------------------------------------
// Fused Q/K/V projection GEMM, split-K 8-wave (unchanged — validated R10).
// ---------------------------------------------------------------------------
__global__ __launch_bounds__(512, 4) void gemm_qkv(
    const float* __restrict__ q, const float* __restrict__ k, const float* __restrict__ v,
    const unsigned short* __restrict__ WtQ, const unsigned short* __restrict__ WtK,
    const unsigned short* __restrict__ WtV,
    unsigned short* __restrict__ Qp, unsigned short* __restrict__ Kp,
    unsigned short* __restrict__ Vt)
{
    __shared__ __align__(16) unsigned short As[2][2][4096];   // [half][buf] 64x64
    __shared__ __align__(16) unsigned short Bs[2][2][4096];

    const int z = blockIdx.z;
    const float* A = z == 0 ? q : (z == 1 ? k : v);
    const unsigned short* Bt = z == 0 ? WtQ : (z == 1 ? WtK : WtV);
    unsigned short* C = z == 0 ? Qp : (z == 1 ? Kp : Vt);
    const bool mode2 = (z == 2);

    const int tid = threadIdx.x;
    const int lane = tid & 63;
    const int w = tid >> 6;            // 0..7
    const int wg = w & 3;              // quadrant wave
    const int half = w >> 2;           // K-half
    const int tidh = tid & 255;        // thread id within half
    const int wm = wg >> 1, wn = wg & 1;
    const int m0 = blockIdx.y * 64;
    const int n0 = blockIdx.x * 64;

    const int srow = lane >> 3;
    const int sgrp = (lane & 7) ^ srow;

    f32x4 acc[2][2];
    #pragma unroll
    for (int i = 0; i < 2; ++i)
        #pragma unroll
        for (int j = 0; j < 2; ++j)
            acc[i][j] = f32x4{0.f, 0.f, 0.f, 0.f};

    auto stageB = [&](int buf, int ktg) {
        const int k0 = ktg * 64;
        #pragma unroll
        for (int cc = 0; cc < 2; ++cc) {
            int call = wg * 2 + cc;
            int row = call * 8 + srow;
            gload_lds16(Bt + (size_t)(n0 + row) * DMODEL + k0 + (sgrp << 3),
                        &Bs[half][buf][call * 512]);
        }
    };

    float4 areg[2][2];
    auto loadA = [&](int ktg) {
        const int k0 = ktg * 64;
        #pragma unroll
        for (int i = 0; i < 2; ++i) {
            int c = i * 256 + tidh;
            int row = c >> 3, g = c & 7;
            const float* p = A + (size_t)(m0 + row) * DMODEL + k0 + g * 8;
            areg[i][0] = *(const float4*)p;
            areg[i][1] = *(const float4*)(p + 4);
        }
    };
    auto writeA = [&](int buf) {
        #pragma unroll
        for (int i = 0; i < 2; ++i) {
            int c = i * 256 + tidh;
            int row = c >> 3, g = c & 7;
            us8 t;
            t[0] = f2bf(areg[i][0].x); t[1] = f2bf(areg[i][0].y);
            t[2] = f2bf(areg[i][0].z); t[3] = f2bf(areg[i][0].w);
            t[4] = f2bf(areg[i][1].x); t[5] = f2bf(areg[i][1].y);
            t[6] = f2bf(areg[i][1].z); t[7] = f2bf(areg[i][1].w);
            *(us8*)&As[half][buf][row * 64 + ((g ^ (row & 7)) << 3)] = t;
        }
    };

    const int frow = lane & 15;
    const int fkg  = lane >> 4;

    auto ldfrag = [&](const unsigned short* base, int rb, int ks) -> bf16x8 {
        int row = rb * 16 + frow;
        int kg = ks * 4 + fkg;
        int off = row * 64 + ((kg ^ (row & 7)) << 3);
        return *(const bf16x8*)&base[off];
    };

    const unsigned short* aB[2] = { mode2 ? Bs[half][0] : As[half][0],
                                    mode2 ? Bs[half][1] : As[half][1] };
    const unsigned short* bB[2] = { mode2 ? As[half][0] : Bs[half][0],
                                    mode2 ? As[half][1] : Bs[half][1] };
    const int ra = mode2 ? wn : wm;
    const int rb_ = mode2 ? wm : wn;

    const int ktbase = half * 4;
    loadA(ktbase);
    stageB(0, ktbase);
    writeA(0);
    __syncthreads();

    for (int t = 0; t < 4; ++t) {
        int buf = t & 1;
        if (t < 3) { loadA(ktbase + t + 1); stageB(buf ^ 1, ktbase + t + 1); }
        #pragma unroll
        for (int ks = 0; ks < 2; ++ks) {
            bf16x8 a0 = ldfrag(aB[buf], ra * 2 + 0, ks);
            bf16x8 a1 = ldfrag(aB[buf], ra * 2 + 1, ks);
            bf16x8 b0 = ldfrag(bB[buf], rb_ * 2 + 0, ks);
            bf16x8 b1 = ldfrag(bB[buf], rb_ * 2 + 1, ks);
            acc[0][0] = __builtin_amdgcn_mfma_f32_16x16x32_bf16(a0, b0, acc[0][0], 0, 0, 0);
            acc[0][1] = __builtin_amdgcn_mfma_f32_16x16x32_bf16(a0, b1, acc[0][1], 0, 0, 0);
            acc[1][0] = __builtin_amdgcn_mfma_f32_16x16x32_bf16(a1, b0, acc[1][0], 0, 0, 0);
            acc[1][1] = __builtin_amdgcn_mfma_f32_16x16x32_bf16(a1, b1, acc[1][1], 0, 0, 0);
        }
        if (t < 3) writeA(buf ^ 1);
        __syncthreads();
    }

    // ---- cross-half reduction via padded LDS scratch (stride 17 floats) ----
    float* red = (float*)&As[0][0][0];
    if (half == 1) {
        int base = (wg * 64 + lane) * 17;
        #pragma unroll
        for (int i = 0; i < 2; ++i)
            #pragma unroll
            for (int j = 0; j < 2; ++j)
                #pragma unroll
                for (int r = 0; r < 4; ++r)
                    red[base + (i * 2 + j) * 4 + r] = acc[i][j][r];
    }
    __syncthreads();
    if (half == 0) {
        int base = (wg * 64 + lane) * 17;
        #pragma unroll
        for (int i = 0; i < 2; ++i)
            #pragma unroll
            for (int j = 0; j < 2; ++j)
                #pragma unroll
                for (int r = 0; r < 4; ++r)
                    acc[i][j][r] += red[base + (i * 2 + j) * 4 + r];

        #pragma unroll
        for (int i = 0; i < 2; ++i) {
            #pragma unroll
            for (int j = 0; j < 2; ++j) {
                #pragma unroll
                for (int r = 0; r < 4; ++r) {
                    if (mode2) {
                        int n = n0 + wn * 32 + i * 16 + (lane >> 4) * 4 + r;
                        int m = m0 + wm * 32 + j * 16 + (lane & 15);
                        int b = m >> 10, jq = m & 1023, h = n >> 6, d = n & 63;
                        C[(((size_t)(b * NH + h) * DHEAD) + d) * LQ + jq] = f2bf(acc[i][j][r]);
                    } else {
                        int m = m0 + wm * 32 + i * 16 + (lane >> 4) * 4 + r;
                        int n = n0 + wn * 32 + j * 16 + (lane & 15);
                        int b = m >> 10, jq = m & 1023, h = n >> 6, d = n & 63;
                        C[(((size_t)(b * NH + h) * LQ) + jq) * DHEAD + d] = f2bf(acc[i][j][r]);
                    }
                }
            }
        }
    }
}

// ---------------------------------------------------------------------------
// FUSED attention + output projection.
// Body through oacc = R7 attn_mfma verbatim (validated incl. post-timing).
// Then: Oh (64q x 64d, this head) -> bf16 LDS bounce Os (wave-private rows)
// -> second MFMA stage vs WtO[n][k] (k-slice = this head's 64 dims, direct
// from global/L2) -> f32 atomicAdd partials into d_out (zeroed by memset).
// out[m][n] = sum over 8 heads of block partials; f32 reassociation only.
// ---------------------------------------------------------------------------
__global__ __launch_bounds__(256) void attn_out(
    const unsigned short* __restrict__ Qp, const unsigned short* __restrict__ Kp,
    const unsigned short* __restrict__ Vt, const unsigned short* __restrict__ WtO,
    float* __restrict__ out)
{
    __shared__ __align__(16) unsigned short Ks[192 * 64];   // 24576 B, XOR-swizzled
    __shared__ __align__(16) unsigned short Vs[64 * 192];   // 24576 B, XOR-swizzled
    __shared__ __align__(16) unsigned short Ps[64 * 200];   // 25600 B, padded rows
    __shared__ __align__(16) unsigned short Os[64][72];     //  9216 B, O bounce

    const int tid = threadIdx.x;
    const int lane = tid & 63;
    const int w = tid >> 6;
    const int bh = blockIdx.y;
    const int j0 = blockIdx.x * 64;
    const int kv0 = j0 - 128;

    const unsigned short* Kg = Kp + (size_t)bh * LQ * DHEAD;
    const unsigned short* Vg = Vt + (size_t)bh * DHEAD * LQ;

    const us8 zz = {0, 0, 0, 0, 0, 0, 0, 0};

    us8 kreg[6];
    #pragma unroll
    for (int i = 0; i < 6; ++i) {
        int c = i * 256 + tid;
        int row = c >> 3, g = c & 7;
        int grow = kv0 + row;
        us8 t = zz;
        if (grow >= 0) t = *(const us8*)&Kg[(size_t)grow * DHEAD + g * 8];
        kreg[i] = t;
    }
    us8 vreg[6];
    #pragma unroll
    for (int i = 0; i < 6; ++i) {
        int c = i * 256 + tid;
        int d = c / 24, g = c - d * 24;
        int col = kv0 + g * 8;
        us8 t = zz;
        if (col >= 0) t = *(const us8*)&Vg[(size_t)d * LQ + col];
        vreg[i] = t;
    }
    #pragma unroll
    for (int i = 0; i < 6; ++i) {
        int c = i * 256 + tid;
        int row = c >> 3, g = c & 7;
        *(us8*)&Ks[row * 64 + ((g ^ (row & 7)) << 3)] = kreg[i];
    }
    #pragma unroll
    for (int i = 0; i < 6; ++i) {
        int c = i * 256 + tid;
        int d = c / 24, g = c - d * 24;
        int sg = (g & ~7) | ((g & 7) ^ (d & 7));
        *(us8*)&Vs[d * 192 + sg * 8] = vreg[i];
    }

    const int frow = lane & 15, fkg = lane >> 4;

    bf16x8 qa[2];
    {
        const unsigned short* Qrow = Qp + ((size_t)bh * LQ + j0 + w * 16 + frow) * DHEAD;
        qa[0] = *(const bf16x8*)&Qrow[fkg * 8];
        qa[1] = *(const bf16x8*)&Qrow[32 + fkg * 8];
    }

    __syncthreads();

    f32x4 sacc[12];
    #pragma unroll
    for (int b = 0; b < 12; ++b) sacc[b] = f32x4{0.f, 0.f, 0.f, 0.f};
    #pragma unroll
    for (int b = 0; b < 12; ++b) {
        #pragma unroll
        for (int ks = 0; ks < 2; ++ks) {
            int row = b * 16 + frow;
            int kg = ks * 4 + fkg;
            bf16x8 kb = *(const bf16x8*)&Ks[row * 64 + ((kg ^ (row & 7)) << 3)];
            sacc[b] = __builtin_amdgcn_mfma_f32_16x16x32_bf16(qa[ks], kb, sacc[b], 0, 0, 0);
        }
    }

    #pragma unroll
    for (int r = 0; r < 4; ++r) {
        int q = w * 16 + fkg * 4 + r;
        float sv[12];
        float mx = -1e30f;
        #pragma unroll
        for (int b = 0; b < 12; ++b) {
            int rel = b * 16 + frow - 128 - q;
            int kvabs = kv0 + b * 16 + frow;
            bool valid = (rel <= 0) & (rel >= -(SPAN - 1)) & (kvabs >= 0);
            float s = valid ? sacc[b][r] * 0.125f : -1e30f;
            sv[b] = s;
            mx = fmaxf(mx, s);
        }
        #pragma unroll
        for (int off = 1; off < 16; off <<= 1) mx = fmaxf(mx, __shfl_xor(mx, off));
        float sum = 0.f;
        #pragma unroll
        for (int b = 0; b < 12; ++b) { float p = __expf(sv[b] - mx); sv[b] = p; sum += p; }
        #pragma unroll
        for (int off = 1; off < 16; off <<= 1) sum += __shfl_xor(sum, off);
        float inv = 1.0f / sum;
        #pragma unroll
        for (int b = 0; b < 12; ++b) sacc[b][r] = sv[b] * inv;
    }

    #pragma unroll
    for (int b = 0; b < 12; ++b) {
        #pragma unroll
        for (int r = 0; r < 4; ++r) {
            int q = w * 16 + fkg * 4 + r;
            Ps[q * 200 + b * 16 + frow] = f2bf(sacc[b][r]);
        }
    }

    f32x4 oacc[4];
    #pragma unroll
    for (int nb = 0; nb < 4; ++nb) oacc[nb] = f32x4{0.f, 0.f, 0.f, 0.f};
    #pragma unroll
    for (int kb = 0; kb < 6; ++kb) {
        int q = w * 16 + frow;
        bf16x8 pa = *(const bf16x8*)&Ps[q * 200 + (kb * 4 + fkg) * 8];
        #pragma unroll
        for (int nb = 0; nb < 4; ++nb) {
            int d = nb * 16 + frow;
            int g = kb * 4 + fkg;
            int sg = (g & ~7) | ((g & 7) ^ (d & 7));
            bf16x8 vb = *(const bf16x8*)&Vs[d * 192 + sg * 8];
            oacc[nb] = __builtin_amdgcn_mfma_f32_16x16x32_bf16(pa, vb, oacc[nb], 0, 0, 0);
        }
    }

    // ---- Oh -> bf16 LDS bounce (wave-private rows; lgkm-ordered reads) ----
    const int b = bh >> 3, h = bh & 7;
    #pragma unroll
    for (int nb = 0; nb < 4; ++nb) {
        #pragma unroll
        for (int r = 0; r < 4; ++r) {
            int q = w * 16 + fkg * 4 + r;      // row within 64-query tile
            Os[q][nb * 16 + frow] = f2bf(oacc[nb][r]);
        }
    }

    // ---- second GEMM: out[64 x 512] partial = Oh @ WtO[h-block][:] ----
    // A-frag: Os row = this wave's query (frow), k-group fkg. B-frag: WtO row
    // n (k-contig, slice k = h*64..h*64+64). Two passes of 16 n-tiles keep
    // register pressure at 64 VGPR for accumulators.
    #pragma unroll
    for (int p = 0; p < 2; ++p) {
        f32x4 oc[16];
        #pragma unroll
        for (int t = 0; t < 16; ++t) oc[t] = f32x4{0.f, 0.f, 0.f, 0.f};
        #pragma unroll
        for (int ks = 0; ks < 2; ++ks) {
            bf16x8 af = *(const bf16x8*)&Os[w * 16 + frow][(ks * 4 + fkg) * 8];
            #pragma unroll
            for (int t = 0; t < 16; ++t) {
                int n = (p * 16 + t) * 16 + frow;
                bf16x8 bw = *(const bf16x8*)&WtO[(size_t)n * DMODEL + h * 64 + (ks * 4 + fkg) * 8];
                oc[t] = __builtin_amdgcn_mfma_f32_16x16x32_bf16(af, bw, oc[t], 0, 0, 0);
            }
        }
        #pragma unroll
        for (int t = 0; t < 16; ++t) {
            #pragma unroll
            for (int r = 0; r < 4; ++r) {
                int m = b * LQ + j0 + w * 16 + fkg * 4 + r;
                int n = (p * 16 + t) * 16 + frow;
                atomicAdd(&out[(size_t)m * DMODEL + n], oc[t][r]);
            }
        }
    }
}

// ---------------------------------------------------------------------------
extern "C" void kernel_launch(void* const* d_in, const int* in_sizes, int n_in,
                              void* d_out, int out_size, void* d_ws, size_t ws_size,
                              hipStream_t stream) {
    const float* q  = (const float*)d_in[0];
    const float* k  = (const float*)d_in[1];
    const float* v  = (const float*)d_in[2];
    const float* Wq = (const float*)d_in[3];
    const float* Wk = (const float*)d_in[4];
    const float* Wv = (const float*)d_in[5];
    const float* Wo = (const float*)d_in[6];

    const size_t MK = (size_t)MROWS * DMODEL;   // 1M elems
    const size_t WK = (size_t)DMODEL * DMODEL;  // 256K elems

    unsigned short* WtQ = (unsigned short*)d_ws;
    unsigned short* WtK = WtQ + WK;
    unsigned short* WtV = WtK + WK;
    unsigned short* WtO = WtV + WK;
    unsigned short* Qp  = WtO + WK;
    unsigned short* Kp  = Qp + MK;
    unsigned short* Vt  = Kp + MK;

    // Zero d_out: attn_out accumulates into it with f32 atomics.
    hipMemsetAsync(d_out, 0, (size_t)MROWS * DMODEL * sizeof(float), stream);

    transposeW<<<dim3(8, 8, 4), 256, 0, stream>>>(Wq, Wk, Wv, Wo, WtQ, WtK, WtV, WtO);

    // Q, K, V projections fused, split-K 8-wave: 768 blocks x 512 threads.
    gemm_qkv<<<dim3(8, 32, 3), 512, 0, stream>>>(q, k, v, WtQ, WtK, WtV, Qp, Kp, Vt);

    // Fused attention + output projection (atomic f32 accumulation).
    attn_out<<<dim3(LQ / 64, 16), 256, 0, stream>>>(Qp, Kp, Vt, WtO, (float*)d_out);
}

// Round 12
// 41.428 us; speedup vs baseline: 1.7337x; 1.7337x over previous
//
#include <hip/hip_runtime.h>
#include <hip/hip_bf16.h>

// B=2, LQ=LKV=1024, H=8, DQK=DV=64, DQ=DK=DVIN=DOUT=512, SPAN=128, STRIDE=1
#define LQ 1024
#define NH 8
#define DHEAD 64
#define DMODEL 512
#define SPAN 128
#define MROWS 2048   // B*LQ

typedef __attribute__((ext_vector_type(8))) short   bf16x8;
typedef __attribute__((ext_vector_type(4))) float   f32x4;
typedef __attribute__((ext_vector_type(8))) unsigned short us8;

static __device__ __forceinline__ unsigned short f2bf(float f) {
    union { __hip_bfloat16 h; unsigned short u; } cv;
    cv.h = __float2bfloat16(f);
    return cv.u;
}

static __device__ __forceinline__ void gload_lds16(const void* g, void* l) {
    __builtin_amdgcn_global_load_lds((const __attribute__((address_space(1))) void*)g,
                                     (__attribute__((address_space(3))) void*)l, 16, 0, 0);
}

// ---------------------------------------------------------------------------
// Prep: transpose+cast weights: Wt[n][k] = bf16(W[k][n]), 512x512 each.
// z==0 (Wq) is PRESCALED by 0.125 (exact bf16 exponent shift) so the
// attention kernel can skip its per-score 1/sqrt(64) multiply.
// ---------------------------------------------------------------------------
__global__ __launch_bounds__(256) void transposeW(
    const float* __restrict__ W0, const float* __restrict__ W1,
    const float* __restrict__ W2, const float* __restrict__ W3,
    unsigned short* __restrict__ T0, unsigned short* __restrict__ T1,
    unsigned short* __restrict__ T2, unsigned short* __restrict__ T3)
{
    const float* W = blockIdx.z == 0 ? W0 : blockIdx.z == 1 ? W1 : blockIdx.z == 2 ? W2 : W3;
    unsigned short* T = blockIdx.z == 0 ? T0 : blockIdx.z == 1 ? T1 : blockIdx.z == 2 ? T2 : T3;
    const float scl = (blockIdx.z == 0) ? 0.125f : 1.0f;
    __shared__ unsigned short sT[64][72];
    int c = threadIdx.x & 63;
    int r0 = (threadIdx.x >> 6) * 16;
    int n0 = blockIdx.x * 64, k0 = blockIdx.y * 64;
    #pragma unroll
    for (int i = 0; i < 16; ++i) {
        int r = r0 + i;
        sT[c][r] = f2bf(W[(size_t)(k0 + r) * DMODEL + n0 + c] * scl);
    }
    __syncthreads();
    #pragma unroll
    for (int i = 0; i < 16; ++i) {
        int r = r0 + i;
        T[(size_t)(n0 + r) * DMODEL + k0 + c] = sT[r][c];
    }
}

// ---------------------------------------------------------------------------
// Fused Q/K/V projection GEMM, split-K 8-wave (unchanged — validated R10).
// ---------------------------------------------------------------------------
__global__ __launch_bounds__(512, 4) void gemm_qkv(
    const float* __restrict__ q, const float* __restrict__ k, const float* __restrict__ v,
    const unsigned short* __restrict__ WtQ, const unsigned short* __restrict__ WtK,
    const unsigned short* __restrict__ WtV,
    unsigned short* __restrict__ Qp, unsigned short* __restrict__ Kp,
    unsigned short* __restrict__ Vt)
{
    __shared__ __align__(16) unsigned short As[2][2][4096];   // [half][buf] 64x64
    __shared__ __align__(16) unsigned short Bs[2][2][4096];

    const int z = blockIdx.z;
    const float* A = z == 0 ? q : (z == 1 ? k : v);
    const unsigned short* Bt = z == 0 ? WtQ : (z == 1 ? WtK : WtV);
    unsigned short* C = z == 0 ? Qp : (z == 1 ? Kp : Vt);
    const bool mode2 = (z == 2);

    const int tid = threadIdx.x;
    const int lane = tid & 63;
    const int w = tid >> 6;            // 0..7
    const int wg = w & 3;              // quadrant wave
    const int half = w >> 2;           // K-half
    const int tidh = tid & 255;        // thread id within half
    const int wm = wg >> 1, wn = wg & 1;
    const int m0 = blockIdx.y * 64;
    const int n0 = blockIdx.x * 64;

    const int srow = lane >> 3;
    const int sgrp = (lane & 7) ^ srow;

    f32x4 acc[2][2];
    #pragma unroll
    for (int i = 0; i < 2; ++i)
        #pragma unroll
        for (int j = 0; j < 2; ++j)
            acc[i][j] = f32x4{0.f, 0.f, 0.f, 0.f};

    auto stageB = [&](int buf, int ktg) {
        const int k0 = ktg * 64;
        #pragma unroll
        for (int cc = 0; cc < 2; ++cc) {
            int call = wg * 2 + cc;
            int row = call * 8 + srow;
            gload_lds16(Bt + (size_t)(n0 + row) * DMODEL + k0 + (sgrp << 3),
                        &Bs[half][buf][call * 512]);
        }
    };

    float4 areg[2][2];
    auto loadA = [&](int ktg) {
        const int k0 = ktg * 64;
        #pragma unroll
        for (int i = 0; i < 2; ++i) {
            int c = i * 256 + tidh;
            int row = c >> 3, g = c & 7;
            const float* p = A + (size_t)(m0 + row) * DMODEL + k0 + g * 8;
            areg[i][0] = *(const float4*)p;
            areg[i][1] = *(const float4*)(p + 4);
        }
    };
    auto writeA = [&](int buf) {
        #pragma unroll
        for (int i = 0; i < 2; ++i) {
            int c = i * 256 + tidh;
            int row = c >> 3, g = c & 7;
            us8 t;
            t[0] = f2bf(areg[i][0].x); t[1] = f2bf(areg[i][0].y);
            t[2] = f2bf(areg[i][0].z); t[3] = f2bf(areg[i][0].w);
            t[4] = f2bf(areg[i][1].x); t[5] = f2bf(areg[i][1].y);
            t[6] = f2bf(areg[i][1].z); t[7] = f2bf(areg[i][1].w);
            *(us8*)&As[half][buf][row * 64 + ((g ^ (row & 7)) << 3)] = t;
        }
    };

    const int frow = lane & 15;
    const int fkg  = lane >> 4;

    auto ldfrag = [&](const unsigned short* base, int rb, int ks) -> bf16x8 {
        int row = rb * 16 + frow;
        int kg = ks * 4 + fkg;
        int off = row * 64 + ((kg ^ (row & 7)) << 3);
        return *(const bf16x8*)&base[off];
    };

    const unsigned short* aB[2] = { mode2 ? Bs[half][0] : As[half][0],
                                    mode2 ? Bs[half][1] : As[half][1] };
    const unsigned short* bB[2] = { mode2 ? As[half][0] : Bs[half][0],
                                    mode2 ? As[half][1] : Bs[half][1] };
    const int ra = mode2 ? wn : wm;
    const int rb_ = mode2 ? wm : wn;

    const int ktbase = half * 4;
    loadA(ktbase);
    stageB(0, ktbase);
    writeA(0);
    __syncthreads();

    for (int t = 0; t < 4; ++t) {
        int buf = t & 1;
        if (t < 3) { loadA(ktbase + t + 1); stageB(buf ^ 1, ktbase + t + 1); }
        #pragma unroll
        for (int ks = 0; ks < 2; ++ks) {
            bf16x8 a0 = ldfrag(aB[buf], ra * 2 + 0, ks);
            bf16x8 a1 = ldfrag(aB[buf], ra * 2 + 1, ks);
            bf16x8 b0 = ldfrag(bB[buf], rb_ * 2 + 0, ks);
            bf16x8 b1 = ldfrag(bB[buf], rb_ * 2 + 1, ks);
            acc[0][0] = __builtin_amdgcn_mfma_f32_16x16x32_bf16(a0, b0, acc[0][0], 0, 0, 0);
            acc[0][1] = __builtin_amdgcn_mfma_f32_16x16x32_bf16(a0, b1, acc[0][1], 0, 0, 0);
            acc[1][0] = __builtin_amdgcn_mfma_f32_16x16x32_bf16(a1, b0, acc[1][0], 0, 0, 0);
            acc[1][1] = __builtin_amdgcn_mfma_f32_16x16x32_bf16(a1, b1, acc[1][1], 0, 0, 0);
        }
        if (t < 3) writeA(buf ^ 1);
        __syncthreads();
    }

    // ---- cross-half reduction via padded LDS scratch (stride 17 floats) ----
    float* red = (float*)&As[0][0][0];
    if (half == 1) {
        int base = (wg * 64 + lane) * 17;
        #pragma unroll
        for (int i = 0; i < 2; ++i)
            #pragma unroll
            for (int j = 0; j < 2; ++j)
                #pragma unroll
                for (int r = 0; r < 4; ++r)
                    red[base + (i * 2 + j) * 4 + r] = acc[i][j][r];
    }
    __syncthreads();
    if (half == 0) {
        int base = (wg * 64 + lane) * 17;
        #pragma unroll
        for (int i = 0; i < 2; ++i)
            #pragma unroll
            for (int j = 0; j < 2; ++j)
                #pragma unroll
                for (int r = 0; r < 4; ++r)
                    acc[i][j][r] += red[base + (i * 2 + j) * 4 + r];

        #pragma unroll
        for (int i = 0; i < 2; ++i) {
            #pragma unroll
            for (int j = 0; j < 2; ++j) {
                #pragma unroll
                for (int r = 0; r < 4; ++r) {
                    if (mode2) {
                        int n = n0 + wn * 32 + i * 16 + (lane >> 4) * 4 + r;
                        int m = m0 + wm * 32 + j * 16 + (lane & 15);
                        int b = m >> 10, jq = m & 1023, h = n >> 6, d = n & 63;
                        C[(((size_t)(b * NH + h) * DHEAD) + d) * LQ + jq] = f2bf(acc[i][j][r]);
                    } else {
                        int m = m0 + wm * 32 + i * 16 + (lane >> 4) * 4 + r;
                        int n = n0 + wn * 32 + j * 16 + (lane & 15);
                        int b = m >> 10, jq = m & 1023, h = n >> 6, d = n & 63;
                        C[(((size_t)(b * NH + h) * LQ) + jq) * DHEAD + d] = f2bf(acc[i][j][r]);
                    }
                }
            }
        }
    }
}

// ---------------------------------------------------------------------------
// Output projection GEMM, split-K 8-wave, 32x64 tiles (unchanged — R10).
// ---------------------------------------------------------------------------
__global__ __launch_bounds__(512, 4) void gemm_out(
    const unsigned short* __restrict__ A, const unsigned short* __restrict__ Bt,
    float* __restrict__ C)
{
    __shared__ __align__(16) unsigned short As[2][2][2048];   // [half][buf] 32x64
    __shared__ __align__(16) unsigned short Bs[2][2][4096];   // [half][buf] 64x64

    const int tid = threadIdx.x;
    const int lane = tid & 63;
    const int w = tid >> 6;
    const int wg = w & 3;
    const int half = w >> 2;
    const int m0 = blockIdx.y * 32;
    const int n0 = blockIdx.x * 64;

    const int srow = lane >> 3;
    const int sgrp = (lane & 7) ^ srow;

    f32x4 acc[2];
    acc[0] = f32x4{0.f, 0.f, 0.f, 0.f};
    acc[1] = f32x4{0.f, 0.f, 0.f, 0.f};

    auto stage = [&](int buf, int ktg) {
        const int k0 = ktg * 64;
        gload_lds16(A + (size_t)(m0 + wg * 8 + srow) * DMODEL + k0 + (sgrp << 3),
                    &As[half][buf][wg * 512]);
        #pragma unroll
        for (int cc = 0; cc < 2; ++cc) {
            int call = wg * 2 + cc;
            int row = call * 8 + srow;
            gload_lds16(Bt + (size_t)(n0 + row) * DMODEL + k0 + (sgrp << 3),
                        &Bs[half][buf][call * 512]);
        }
    };

    const int frow = lane & 15;
    const int fkg  = lane >> 4;

    auto ldfrag = [&](const unsigned short* base, int rb, int ks) -> bf16x8 {
        int row = rb * 16 + frow;
        int kg = ks * 4 + fkg;
        int off = row * 64 + ((kg ^ (row & 7)) << 3);
        return *(const bf16x8*)&base[off];
    };

    const int ktbase = half * 4;
    stage(0, ktbase);
    __syncthreads();

    for (int t = 0; t < 4; ++t) {
        int buf = t & 1;
        if (t < 3) stage(buf ^ 1, ktbase + t + 1);
        #pragma unroll
        for (int ks = 0; ks < 2; ++ks) {
            bf16x8 a0 = ldfrag(As[half][buf], 0, ks);
            bf16x8 a1 = ldfrag(As[half][buf], 1, ks);
            bf16x8 b0 = ldfrag(Bs[half][buf], wg, ks);
            acc[0] = __builtin_amdgcn_mfma_f32_16x16x32_bf16(a0, b0, acc[0], 0, 0, 0);
            acc[1] = __builtin_amdgcn_mfma_f32_16x16x32_bf16(a1, b0, acc[1], 0, 0, 0);
        }
        __syncthreads();
    }

    // ---- cross-half reduction (stride 9 floats: conflict-free) ----
    float* red = (float*)&As[0][0][0];
    if (half == 1) {
        int base = (wg * 64 + lane) * 9;
        #pragma unroll
        for (int i = 0; i < 2; ++i)
            #pragma unroll
            for (int r = 0; r < 4; ++r)
                red[base + i * 4 + r] = acc[i][r];
    }
    __syncthreads();
    if (half == 0) {
        int base = (wg * 64 + lane) * 9;
        #pragma unroll
        for (int i = 0; i < 2; ++i) {
            #pragma unroll
            for (int r = 0; r < 4; ++r) {
                float vsum = acc[i][r] + red[base + i * 4 + r];
                int m = m0 + i * 16 + (lane >> 4) * 4 + r;
                int n = n0 + wg * 16 + (lane & 15);
                C[(size_t)m * DMODEL + n] = vsum;
            }
        }
    }
}

// ---------------------------------------------------------------------------
// MFMA sliding-window attention (R7 body — best measured, validated incl.
// post-timing) with two micro-changes:
//  (1) no per-score *0.125 (WtQ prescaled in transposeW),
//  (2) softmax normalization deferred: P stored unnormalized, 1/sum applied
//      to the PV accumulator at the end (48 mults -> 16).
// ---------------------------------------------------------------------------
__global__ __launch_bounds__(256) void attn_mfma(
    const unsigned short* __restrict__ Qp, const unsigned short* __restrict__ Kp,
    const unsigned short* __restrict__ Vt, unsigned short* __restrict__ O)
{
    __shared__ __align__(16) unsigned short Ks[192 * 64];   // 24576 B, XOR-swizzled
    __shared__ __align__(16) unsigned short Vs[64 * 192];   // 24576 B, XOR-swizzled
    __shared__ __align__(16) unsigned short Ps[64 * 200];   // 25600 B, padded rows

    const int tid = threadIdx.x;
    const int lane = tid & 63;
    const int w = tid >> 6;
    const int bh = blockIdx.y;
    const int j0 = blockIdx.x * 64;
    const int kv0 = j0 - 128;

    const unsigned short* Kg = Kp + (size_t)bh * LQ * DHEAD;
    const unsigned short* Vg = Vt + (size_t)bh * DHEAD * LQ;

    const us8 zz = {0, 0, 0, 0, 0, 0, 0, 0};

    us8 kreg[6];
    #pragma unroll
    for (int i = 0; i < 6; ++i) {
        int c = i * 256 + tid;
        int row = c >> 3, g = c & 7;
        int grow = kv0 + row;
        us8 t = zz;
        if (grow >= 0) t = *(const us8*)&Kg[(size_t)grow * DHEAD + g * 8];
        kreg[i] = t;
    }
    us8 vreg[6];
    #pragma unroll
    for (int i = 0; i < 6; ++i) {
        int c = i * 256 + tid;
        int d = c / 24, g = c - d * 24;
        int col = kv0 + g * 8;
        us8 t = zz;
        if (col >= 0) t = *(const us8*)&Vg[(size_t)d * LQ + col];
        vreg[i] = t;
    }
    #pragma unroll
    for (int i = 0; i < 6; ++i) {
        int c = i * 256 + tid;
        int row = c >> 3, g = c & 7;
        *(us8*)&Ks[row * 64 + ((g ^ (row & 7)) << 3)] = kreg[i];
    }
    #pragma unroll
    for (int i = 0; i < 6; ++i) {
        int c = i * 256 + tid;
        int d = c / 24, g = c - d * 24;
        int sg = (g & ~7) | ((g & 7) ^ (d & 7));
        *(us8*)&Vs[d * 192 + sg * 8] = vreg[i];
    }

    const int frow = lane & 15, fkg = lane >> 4;

    bf16x8 qa[2];
    {
        const unsigned short* Qrow = Qp + ((size_t)bh * LQ + j0 + w * 16 + frow) * DHEAD;
        qa[0] = *(const bf16x8*)&Qrow[fkg * 8];
        qa[1] = *(const bf16x8*)&Qrow[32 + fkg * 8];
    }

    __syncthreads();

    f32x4 sacc[12];
    #pragma unroll
    for (int b = 0; b < 12; ++b) sacc[b] = f32x4{0.f, 0.f, 0.f, 0.f};
    #pragma unroll
    for (int b = 0; b < 12; ++b) {
        #pragma unroll
        for (int ks = 0; ks < 2; ++ks) {
            int row = b * 16 + frow;
            int kg = ks * 4 + fkg;
            bf16x8 kb = *(const bf16x8*)&Ks[row * 64 + ((kg ^ (row & 7)) << 3)];
            sacc[b] = __builtin_amdgcn_mfma_f32_16x16x32_bf16(qa[ks], kb, sacc[b], 0, 0, 0);
        }
    }

    // ---- mask + softmax; normalization deferred to the PV epilogue ----
    float inv4[4];
    #pragma unroll
    for (int r = 0; r < 4; ++r) {
        int q = w * 16 + fkg * 4 + r;
        float sv[12];
        float mx = -1e30f;
        #pragma unroll
        for (int b = 0; b < 12; ++b) {
            int rel = b * 16 + frow - 128 - q;
            int kvabs = kv0 + b * 16 + frow;
            bool valid = (rel <= 0) & (rel >= -(SPAN - 1)) & (kvabs >= 0);
            float s = valid ? sacc[b][r] : -1e30f;   // scores pre-scaled via WtQ
            sv[b] = s;
            mx = fmaxf(mx, s);
        }
        #pragma unroll
        for (int off = 1; off < 16; off <<= 1) mx = fmaxf(mx, __shfl_xor(mx, off));
        float sum = 0.f;
        #pragma unroll
        for (int b = 0; b < 12; ++b) { float p = __expf(sv[b] - mx); sv[b] = p; sum += p; }
        #pragma unroll
        for (int off = 1; off < 16; off <<= 1) sum += __shfl_xor(sum, off);
        inv4[r] = 1.0f / sum;
        #pragma unroll
        for (int b = 0; b < 12; ++b) sacc[b][r] = sv[b];   // unnormalized P
    }

    #pragma unroll
    for (int b = 0; b < 12; ++b) {
        #pragma unroll
        for (int r = 0; r < 4; ++r) {
            int q = w * 16 + fkg * 4 + r;
            Ps[q * 200 + b * 16 + frow] = f2bf(sacc[b][r]);
        }
    }

    f32x4 oacc[4];
    #pragma unroll
    for (int nb = 0; nb < 4; ++nb) oacc[nb] = f32x4{0.f, 0.f, 0.f, 0.f};
    #pragma unroll
    for (int kb = 0; kb < 6; ++kb) {
        int q = w * 16 + frow;
        bf16x8 pa = *(const bf16x8*)&Ps[q * 200 + (kb * 4 + fkg) * 8];
        #pragma unroll
        for (int nb = 0; nb < 4; ++nb) {
            int d = nb * 16 + frow;
            int g = kb * 4 + fkg;
            int sg = (g & ~7) | ((g & 7) ^ (d & 7));
            bf16x8 vb = *(const bf16x8*)&Vs[d * 192 + sg * 8];
            oacc[nb] = __builtin_amdgcn_mfma_f32_16x16x32_bf16(pa, vb, oacc[nb], 0, 0, 0);
        }
    }

    // ---- write O with deferred normalization (row r <-> query fkg*4+r) ----
    int b = bh >> 3, h = bh & 7;
    #pragma unroll
    for (int nb = 0; nb < 4; ++nb) {
        #pragma unroll
        for (int r = 0; r < 4; ++r) {
            int jq = j0 + w * 16 + fkg * 4 + r;
            int col = h * 64 + nb * 16 + frow;
            O[(size_t)(b * LQ + jq) * DMODEL + col] = f2bf(oacc[nb][r] * inv4[r]);
        }
    }
}

// ---------------------------------------------------------------------------
extern "C" void kernel_launch(void* const* d_in, const int* in_sizes, int n_in,
                              void* d_out, int out_size, void* d_ws, size_t ws_size,
                              hipStream_t stream) {
    const float* q  = (const float*)d_in[0];
    const float* k  = (const float*)d_in[1];
    const float* v  = (const float*)d_in[2];
    const float* Wq = (const float*)d_in[3];
    const float* Wk = (const float*)d_in[4];
    const float* Wv = (const float*)d_in[5];
    const float* Wo = (const float*)d_in[6];

    const size_t MK = (size_t)MROWS * DMODEL;   // 1M elems
    const size_t WK = (size_t)DMODEL * DMODEL;  // 256K elems

    unsigned short* WtQ = (unsigned short*)d_ws;
    unsigned short* WtK = WtQ + WK;
    unsigned short* WtV = WtK + WK;
    unsigned short* WtO = WtV + WK;
    unsigned short* Qp  = WtO + WK;
    unsigned short* Kp  = Qp + MK;
    unsigned short* Vt  = Kp + MK;
    unsigned short* Ah  = Vt + MK;

    transposeW<<<dim3(8, 8, 4), 256, 0, stream>>>(Wq, Wk, Wv, Wo, WtQ, WtK, WtV, WtO);

    // Q, K, V projections fused, split-K 8-wave: 768 blocks x 512 threads.
    gemm_qkv<<<dim3(8, 32, 3), 512, 0, stream>>>(q, k, v, WtQ, WtK, WtV, Qp, Kp, Vt);

    // Attention: R7 structure + prescaled scores + deferred normalization.
    attn_mfma<<<dim3(LQ / 64, 16), 256, 0, stream>>>(Qp, Kp, Vt, Ah);

    // Output projection: split-K 8-wave, 32x64 tiles, 512 blocks.
    gemm_out<<<dim3(8, 64), 512, 0, stream>>>(Ah, WtO, (float*)d_out);
}

// Round 13
// 33.881 us; speedup vs baseline: 2.1198x; 1.2227x over previous
//
#include <hip/hip_runtime.h>
#include <hip/hip_bf16.h>

// B=2, LQ=LKV=1024, H=8, DQK=DV=64, DQ=DK=DVIN=DOUT=512, SPAN=128, STRIDE=1
#define LQ 1024
#define NH 8
#define DHEAD 64
#define DMODEL 512
#define SPAN 128
#define MROWS 2048   // B*LQ

typedef __attribute__((ext_vector_type(8))) short   bf16x8;
typedef __attribute__((ext_vector_type(4))) float   f32x4;
typedef __attribute__((ext_vector_type(8))) unsigned short us8;

static __device__ __forceinline__ unsigned short f2bf(float f) {
    union { __hip_bfloat16 h; unsigned short u; } cv;
    cv.h = __float2bfloat16(f);
    return cv.u;
}

static __device__ __forceinline__ void gload_lds16(const void* g, void* l) {
    __builtin_amdgcn_global_load_lds((const __attribute__((address_space(1))) void*)g,
                                     (__attribute__((address_space(3))) void*)l, 16, 0, 0);
}

// ---------------------------------------------------------------------------
// Prep: transpose+cast weights: Wt[n][k] = bf16(W[k][n]), 512x512 each.
// Wq prescaled by 0.125 (exact bf16 exponent shift). (unchanged — validated)
// ---------------------------------------------------------------------------
__global__ __launch_bounds__(256) void transposeW(
    const float* __restrict__ W0, const float* __restrict__ W1,
    const float* __restrict__ W2, const float* __restrict__ W3,
    unsigned short* __restrict__ T0, unsigned short* __restrict__ T1,
    unsigned short* __restrict__ T2, unsigned short* __restrict__ T3)
{
    const float* W = blockIdx.z == 0 ? W0 : blockIdx.z == 1 ? W1 : blockIdx.z == 2 ? W2 : W3;
    unsigned short* T = blockIdx.z == 0 ? T0 : blockIdx.z == 1 ? T1 : blockIdx.z == 2 ? T2 : T3;
    const float scl = (blockIdx.z == 0) ? 0.125f : 1.0f;
    __shared__ unsigned short sT[64][72];
    int c = threadIdx.x & 63;
    int r0 = (threadIdx.x >> 6) * 16;
    int n0 = blockIdx.x * 64, k0 = blockIdx.y * 64;
    #pragma unroll
    for (int i = 0; i < 16; ++i) {
        int r = r0 + i;
        sT[c][r] = f2bf(W[(size_t)(k0 + r) * DMODEL + n0 + c] * scl);
    }
    __syncthreads();
    #pragma unroll
    for (int i = 0; i < 16; ++i) {
        int r = r0 + i;
        T[(size_t)(n0 + r) * DMODEL + k0 + c] = sT[r][c];
    }
}

// ---------------------------------------------------------------------------
// Fused Q/K/V projection GEMM, split-K 8-wave (R10-validated) + T1 XCD
// swizzle: hw XCD = (y*8+x)%8; remap so each XCD owns m-chunk [4X,4X+4) for
// ALL n-tiles -> per-XCD L2 working set ~1 MB (A-panels + whole B), cutting
// through-L3 A re-reads 8x. Pure index permutation, numerics untouched.
// ---------------------------------------------------------------------------
__global__ __launch_bounds__(512, 4) void gemm_qkv(
    const float* __restrict__ q, const float* __restrict__ k, const float* __restrict__ v,
    const unsigned short* __restrict__ WtQ, const unsigned short* __restrict__ WtK,
    const unsigned short* __restrict__ WtV,
    unsigned short* __restrict__ Qp, unsigned short* __restrict__ Kp,
    unsigned short* __restrict__ Vt)
{
    __shared__ __align__(16) unsigned short As[2][2][4096];   // [half][buf] 64x64
    __shared__ __align__(16) unsigned short Bs[2][2][4096];

    const int z = blockIdx.z;
    const float* A = z == 0 ? q : (z == 1 ? k : v);
    const unsigned short* Bt = z == 0 ? WtQ : (z == 1 ? WtK : WtV);
    unsigned short* C = z == 0 ? Qp : (z == 1 ? Kp : Vt);
    const bool mode2 = (z == 2);

    // T1 swizzle: t%8 = hw XCD; give it vid-chunk of 32 = 4 m-tiles x 8 n.
    const int t_ = blockIdx.y * 8 + blockIdx.x;
    const int vid = (t_ & 7) * 32 + (t_ >> 3);
    const int bx = vid & 7;
    const int by = vid >> 3;

    const int tid = threadIdx.x;
    const int lane = tid & 63;
    const int w = tid >> 6;            // 0..7
    const int wg = w & 3;              // quadrant wave
    const int half = w >> 2;           // K-half
    const int tidh = tid & 255;        // thread id within half
    const int wm = wg >> 1, wn = wg & 1;
    const int m0 = by * 64;
    const int n0 = bx * 64;

    const int srow = lane >> 3;
    const int sgrp = (lane & 7) ^ srow;

    f32x4 acc[2][2];
    #pragma unroll
    for (int i = 0; i < 2; ++i)
        #pragma unroll
        for (int j = 0; j < 2; ++j)
            acc[i][j] = f32x4{0.f, 0.f, 0.f, 0.f};

    auto stageB = [&](int buf, int ktg) {
        const int k0 = ktg * 64;
        #pragma unroll
        for (int cc = 0; cc < 2; ++cc) {
            int call = wg * 2 + cc;
            int row = call * 8 + srow;
            gload_lds16(Bt + (size_t)(n0 + row) * DMODEL + k0 + (sgrp << 3),
                        &Bs[half][buf][call * 512]);
        }
    };

    float4 areg[2][2];
    auto loadA = [&](int ktg) {
        const int k0 = ktg * 64;
        #pragma unroll
        for (int i = 0; i < 2; ++i) {
            int c = i * 256 + tidh;
            int row = c >> 3, g = c & 7;
            const float* p = A + (size_t)(m0 + row) * DMODEL + k0 + g * 8;
            areg[i][0] = *(const float4*)p;
            areg[i][1] = *(const float4*)(p + 4);
        }
    };
    auto writeA = [&](int buf) {
        #pragma unroll
        for (int i = 0; i < 2; ++i) {
            int c = i * 256 + tidh;
            int row = c >> 3, g = c & 7;
            us8 t;
            t[0] = f2bf(areg[i][0].x); t[1] = f2bf(areg[i][0].y);
            t[2] = f2bf(areg[i][0].z); t[3] = f2bf(areg[i][0].w);
            t[4] = f2bf(areg[i][1].x); t[5] = f2bf(areg[i][1].y);
            t[6] = f2bf(areg[i][1].z); t[7] = f2bf(areg[i][1].w);
            *(us8*)&As[half][buf][row * 64 + ((g ^ (row & 7)) << 3)] = t;
        }
    };

    const int frow = lane & 15;
    const int fkg  = lane >> 4;

    auto ldfrag = [&](const unsigned short* base, int rb, int ks) -> bf16x8 {
        int row = rb * 16 + frow;
        int kg = ks * 4 + fkg;
        int off = row * 64 + ((kg ^ (row & 7)) << 3);
        return *(const bf16x8*)&base[off];
    };

    const unsigned short* aB[2] = { mode2 ? Bs[half][0] : As[half][0],
                                    mode2 ? Bs[half][1] : As[half][1] };
    const unsigned short* bB[2] = { mode2 ? As[half][0] : Bs[half][0],
                                    mode2 ? As[half][1] : Bs[half][1] };
    const int ra = mode2 ? wn : wm;
    const int rb_ = mode2 ? wm : wn;

    const int ktbase = half * 4;
    loadA(ktbase);
    stageB(0, ktbase);
    writeA(0);
    __syncthreads();

    for (int t = 0; t < 4; ++t) {
        int buf = t & 1;
        if (t < 3) { loadA(ktbase + t + 1); stageB(buf ^ 1, ktbase + t + 1); }
        #pragma unroll
        for (int ks = 0; ks < 2; ++ks) {
            bf16x8 a0 = ldfrag(aB[buf], ra * 2 + 0, ks);
            bf16x8 a1 = ldfrag(aB[buf], ra * 2 + 1, ks);
            bf16x8 b0 = ldfrag(bB[buf], rb_ * 2 + 0, ks);
            bf16x8 b1 = ldfrag(bB[buf], rb_ * 2 + 1, ks);
            acc[0][0] = __builtin_amdgcn_mfma_f32_16x16x32_bf16(a0, b0, acc[0][0], 0, 0, 0);
            acc[0][1] = __builtin_amdgcn_mfma_f32_16x16x32_bf16(a0, b1, acc[0][1], 0, 0, 0);
            acc[1][0] = __builtin_amdgcn_mfma_f32_16x16x32_bf16(a1, b0, acc[1][0], 0, 0, 0);
            acc[1][1] = __builtin_amdgcn_mfma_f32_16x16x32_bf16(a1, b1, acc[1][1], 0, 0, 0);
        }
        if (t < 3) writeA(buf ^ 1);
        __syncthreads();
    }

    // ---- cross-half reduction via padded LDS scratch (stride 17 floats) ----
    float* red = (float*)&As[0][0][0];
    if (half == 1) {
        int base = (wg * 64 + lane) * 17;
        #pragma unroll
        for (int i = 0; i < 2; ++i)
            #pragma unroll
            for (int j = 0; j < 2; ++j)
                #pragma unroll
                for (int r = 0; r < 4; ++r)
                    red[base + (i * 2 + j) * 4 + r] = acc[i][j][r];
    }
    __syncthreads();
    if (half == 0) {
        int base = (wg * 64 + lane) * 17;
        #pragma unroll
        for (int i = 0; i < 2; ++i)
            #pragma unroll
            for (int j = 0; j < 2; ++j)
                #pragma unroll
                for (int r = 0; r < 4; ++r)
                    acc[i][j][r] += red[base + (i * 2 + j) * 4 + r];

        #pragma unroll
        for (int i = 0; i < 2; ++i) {
            #pragma unroll
            for (int j = 0; j < 2; ++j) {
                #pragma unroll
                for (int r = 0; r < 4; ++r) {
                    if (mode2) {
                        int n = n0 + wn * 32 + i * 16 + (lane >> 4) * 4 + r;
                        int m = m0 + wm * 32 + j * 16 + (lane & 15);
                        int b = m >> 10, jq = m & 1023, h = n >> 6, d = n & 63;
                        C[(((size_t)(b * NH + h) * DHEAD) + d) * LQ + jq] = f2bf(acc[i][j][r]);
                    } else {
                        int m = m0 + wm * 32 + i * 16 + (lane >> 4) * 4 + r;
                        int n = n0 + wn * 32 + j * 16 + (lane & 15);
                        int b = m >> 10, jq = m & 1023, h = n >> 6, d = n & 63;
                        C[(((size_t)(b * NH + h) * LQ) + jq) * DHEAD + d] = f2bf(acc[i][j][r]);
                    }
                }
            }
        }
    }
}

// ---------------------------------------------------------------------------
// Output projection GEMM, split-K 8-wave, 32x64 tiles (R10) + T1 XCD swizzle:
// each XCD owns m-chunk [8X,8X+8) for all n-tiles.
// ---------------------------------------------------------------------------
__global__ __launch_bounds__(512, 4) void gemm_out(
    const unsigned short* __restrict__ A, const unsigned short* __restrict__ Bt,
    float* __restrict__ C)
{
    __shared__ __align__(16) unsigned short As[2][2][2048];   // [half][buf] 32x64
    __shared__ __align__(16) unsigned short Bs[2][2][4096];   // [half][buf] 64x64

    // T1 swizzle over 512 blocks: chunk of 64 vids per XCD.
    const int t_ = blockIdx.y * 8 + blockIdx.x;
    const int vid = (t_ & 7) * 64 + (t_ >> 3);
    const int bx = vid & 7;
    const int by = vid >> 3;

    const int tid = threadIdx.x;
    const int lane = tid & 63;
    const int w = tid >> 6;
    const int wg = w & 3;
    const int half = w >> 2;
    const int m0 = by * 32;
    const int n0 = bx * 64;

    const int srow = lane >> 3;
    const int sgrp = (lane & 7) ^ srow;

    f32x4 acc[2];
    acc[0] = f32x4{0.f, 0.f, 0.f, 0.f};
    acc[1] = f32x4{0.f, 0.f, 0.f, 0.f};

    auto stage = [&](int buf, int ktg) {
        const int k0 = ktg * 64;
        gload_lds16(A + (size_t)(m0 + wg * 8 + srow) * DMODEL + k0 + (sgrp << 3),
                    &As[half][buf][wg * 512]);
        #pragma unroll
        for (int cc = 0; cc < 2; ++cc) {
            int call = wg * 2 + cc;
            int row = call * 8 + srow;
            gload_lds16(Bt + (size_t)(n0 + row) * DMODEL + k0 + (sgrp << 3),
                        &Bs[half][buf][call * 512]);
        }
    };

    const int frow = lane & 15;
    const int fkg  = lane >> 4;

    auto ldfrag = [&](const unsigned short* base, int rb, int ks) -> bf16x8 {
        int row = rb * 16 + frow;
        int kg = ks * 4 + fkg;
        int off = row * 64 + ((kg ^ (row & 7)) << 3);
        return *(const bf16x8*)&base[off];
    };

    const int ktbase = half * 4;
    stage(0, ktbase);
    __syncthreads();

    for (int t = 0; t < 4; ++t) {
        int buf = t & 1;
        if (t < 3) stage(buf ^ 1, ktbase + t + 1);
        #pragma unroll
        for (int ks = 0; ks < 2; ++ks) {
            bf16x8 a0 = ldfrag(As[half][buf], 0, ks);
            bf16x8 a1 = ldfrag(As[half][buf], 1, ks);
            bf16x8 b0 = ldfrag(Bs[half][buf], wg, ks);
            acc[0] = __builtin_amdgcn_mfma_f32_16x16x32_bf16(a0, b0, acc[0], 0, 0, 0);
            acc[1] = __builtin_amdgcn_mfma_f32_16x16x32_bf16(a1, b0, acc[1], 0, 0, 0);
        }
        __syncthreads();
    }

    // ---- cross-half reduction (stride 9 floats: conflict-free) ----
    float* red = (float*)&As[0][0][0];
    if (half == 1) {
        int base = (wg * 64 + lane) * 9;
        #pragma unroll
        for (int i = 0; i < 2; ++i)
            #pragma unroll
            for (int r = 0; r < 4; ++r)
                red[base + i * 4 + r] = acc[i][r];
    }
    __syncthreads();
    if (half == 0) {
        int base = (wg * 64 + lane) * 9;
        #pragma unroll
        for (int i = 0; i < 2; ++i) {
            #pragma unroll
            for (int r = 0; r < 4; ++r) {
                float vsum = acc[i][r] + red[base + i * 4 + r];
                int m = m0 + i * 16 + (lane >> 4) * 4 + r;
                int n = n0 + wg * 16 + (lane & 15);
                C[(size_t)m * DMODEL + n] = vsum;
            }
        }
    }
}

// ---------------------------------------------------------------------------
// MFMA sliding-window attention (R12 body: prescaled scores + deferred
// normalization) + T1 XCD swizzle: 2 heads per XCD, overlapping j-tiles of
// the same head colocate so shared K/V window rows become L2 hits.
// ---------------------------------------------------------------------------
__global__ __launch_bounds__(256) void attn_mfma(
    const unsigned short* __restrict__ Qp, const unsigned short* __restrict__ Kp,
    const unsigned short* __restrict__ Vt, unsigned short* __restrict__ O)
{
    __shared__ __align__(16) unsigned short Ks[192 * 64];   // 24576 B, XOR-swizzled
    __shared__ __align__(16) unsigned short Vs[64 * 192];   // 24576 B, XOR-swizzled
    __shared__ __align__(16) unsigned short Ps[64 * 200];   // 25600 B, padded rows

    // T1 swizzle over 256 blocks (grid 16x16): 2 bh + all 16 j-tiles per XCD.
    const int t_ = blockIdx.y * 16 + blockIdx.x;
    const int vid = (t_ & 7) * 32 + (t_ >> 3);

    const int tid = threadIdx.x;
    const int lane = tid & 63;
    const int w = tid >> 6;
    const int bh = vid >> 4;
    const int j0 = (vid & 15) * 64;
    const int kv0 = j0 - 128;

    const unsigned short* Kg = Kp + (size_t)bh * LQ * DHEAD;
    const unsigned short* Vg = Vt + (size_t)bh * DHEAD * LQ;

    const us8 zz = {0, 0, 0, 0, 0, 0, 0, 0};

    us8 kreg[6];
    #pragma unroll
    for (int i = 0; i < 6; ++i) {
        int c = i * 256 + tid;
        int row = c >> 3, g = c & 7;
        int grow = kv0 + row;
        us8 t = zz;
        if (grow >= 0) t = *(const us8*)&Kg[(size_t)grow * DHEAD + g * 8];
        kreg[i] = t;
    }
    us8 vreg[6];
    #pragma unroll
    for (int i = 0; i < 6; ++i) {
        int c = i * 256 + tid;
        int d = c / 24, g = c - d * 24;
        int col = kv0 + g * 8;
        us8 t = zz;
        if (col >= 0) t = *(const us8*)&Vg[(size_t)d * LQ + col];
        vreg[i] = t;
    }
    #pragma unroll
    for (int i = 0; i < 6; ++i) {
        int c = i * 256 + tid;
        int row = c >> 3, g = c & 7;
        *(us8*)&Ks[row * 64 + ((g ^ (row & 7)) << 3)] = kreg[i];
    }
    #pragma unroll
    for (int i = 0; i < 6; ++i) {
        int c = i * 256 + tid;
        int d = c / 24, g = c - d * 24;
        int sg = (g & ~7) | ((g & 7) ^ (d & 7));
        *(us8*)&Vs[d * 192 + sg * 8] = vreg[i];
    }

    const int frow = lane & 15, fkg = lane >> 4;

    bf16x8 qa[2];
    {
        const unsigned short* Qrow = Qp + ((size_t)bh * LQ + j0 + w * 16 + frow) * DHEAD;
        qa[0] = *(const bf16x8*)&Qrow[fkg * 8];
        qa[1] = *(const bf16x8*)&Qrow[32 + fkg * 8];
    }

    __syncthreads();

    f32x4 sacc[12];
    #pragma unroll
    for (int b = 0; b < 12; ++b) sacc[b] = f32x4{0.f, 0.f, 0.f, 0.f};
    #pragma unroll
    for (int b = 0; b < 12; ++b) {
        #pragma unroll
        for (int ks = 0; ks < 2; ++ks) {
            int row = b * 16 + frow;
            int kg = ks * 4 + fkg;
            bf16x8 kb = *(const bf16x8*)&Ks[row * 64 + ((kg ^ (row & 7)) << 3)];
            sacc[b] = __builtin_amdgcn_mfma_f32_16x16x32_bf16(qa[ks], kb, sacc[b], 0, 0, 0);
        }
    }

    // ---- mask + softmax; normalization deferred to the PV epilogue ----
    float inv4[4];
    #pragma unroll
    for (int r = 0; r < 4; ++r) {
        int q = w * 16 + fkg * 4 + r;
        float sv[12];
        float mx = -1e30f;
        #pragma unroll
        for (int b = 0; b < 12; ++b) {
            int rel = b * 16 + frow - 128 - q;
            int kvabs = kv0 + b * 16 + frow;
            bool valid = (rel <= 0) & (rel >= -(SPAN - 1)) & (kvabs >= 0);
            float s = valid ? sacc[b][r] : -1e30f;   // scores pre-scaled via WtQ
            sv[b] = s;
            mx = fmaxf(mx, s);
        }
        #pragma unroll
        for (int off = 1; off < 16; off <<= 1) mx = fmaxf(mx, __shfl_xor(mx, off));
        float sum = 0.f;
        #pragma unroll
        for (int b = 0; b < 12; ++b) { float p = __expf(sv[b] - mx); sv[b] = p; sum += p; }
        #pragma unroll
        for (int off = 1; off < 16; off <<= 1) sum += __shfl_xor(sum, off);
        inv4[r] = 1.0f / sum;
        #pragma unroll
        for (int b = 0; b < 12; ++b) sacc[b][r] = sv[b];   // unnormalized P
    }

    #pragma unroll
    for (int b = 0; b < 12; ++b) {
        #pragma unroll
        for (int r = 0; r < 4; ++r) {
            int q = w * 16 + fkg * 4 + r;
            Ps[q * 200 + b * 16 + frow] = f2bf(sacc[b][r]);
        }
    }

    f32x4 oacc[4];
    #pragma unroll
    for (int nb = 0; nb < 4; ++nb) oacc[nb] = f32x4{0.f, 0.f, 0.f, 0.f};
    #pragma unroll
    for (int kb = 0; kb < 6; ++kb) {
        int q = w * 16 + frow;
        bf16x8 pa = *(const bf16x8*)&Ps[q * 200 + (kb * 4 + fkg) * 8];
        #pragma unroll
        for (int nb = 0; nb < 4; ++nb) {
            int d = nb * 16 + frow;
            int g = kb * 4 + fkg;
            int sg = (g & ~7) | ((g & 7) ^ (d & 7));
            bf16x8 vb = *(const bf16x8*)&Vs[d * 192 + sg * 8];
            oacc[nb] = __builtin_amdgcn_mfma_f32_16x16x32_bf16(pa, vb, oacc[nb], 0, 0, 0);
        }
    }

    // ---- write O with deferred normalization ----
    int b = bh >> 3, h = bh & 7;
    #pragma unroll
    for (int nb = 0; nb < 4; ++nb) {
        #pragma unroll
        for (int r = 0; r < 4; ++r) {
            int jq = j0 + w * 16 + fkg * 4 + r;
            int col = h * 64 + nb * 16 + frow;
            O[(size_t)(b * LQ + jq) * DMODEL + col] = f2bf(oacc[nb][r] * inv4[r]);
        }
    }
}

// ---------------------------------------------------------------------------
extern "C" void kernel_launch(void* const* d_in, const int* in_sizes, int n_in,
                              void* d_out, int out_size, void* d_ws, size_t ws_size,
                              hipStream_t stream) {
    const float* q  = (const float*)d_in[0];
    const float* k  = (const float*)d_in[1];
    const float* v  = (const float*)d_in[2];
    const float* Wq = (const float*)d_in[3];
    const float* Wk = (const float*)d_in[4];
    const float* Wv = (const float*)d_in[5];
    const float* Wo = (const float*)d_in[6];

    const size_t MK = (size_t)MROWS * DMODEL;   // 1M elems
    const size_t WK = (size_t)DMODEL * DMODEL;  // 256K elems

    unsigned short* WtQ = (unsigned short*)d_ws;
    unsigned short* WtK = WtQ + WK;
    unsigned short* WtV = WtK + WK;
    unsigned short* WtO = WtV + WK;
    unsigned short* Qp  = WtO + WK;
    unsigned short* Kp  = Qp + MK;
    unsigned short* Vt  = Kp + MK;
    unsigned short* Ah  = Vt + MK;

    transposeW<<<dim3(8, 8, 4), 256, 0, stream>>>(Wq, Wk, Wv, Wo, WtQ, WtK, WtV, WtO);

    // Q, K, V projections fused, split-K 8-wave + XCD swizzle.
    gemm_qkv<<<dim3(8, 32, 3), 512, 0, stream>>>(q, k, v, WtQ, WtK, WtV, Qp, Kp, Vt);

    // Attention: R12 structure + XCD swizzle.
    attn_mfma<<<dim3(16, 16), 256, 0, stream>>>(Qp, Kp, Vt, Ah);

    // Output projection: split-K 8-wave, 32x64 tiles + XCD swizzle.
    gemm_out<<<dim3(8, 64), 512, 0, stream>>>(Ah, WtO, (float*)d_out);
}